// Round 1
// baseline (3810.412 us; speedup 1.0000x reference)
//
#include <hip/hip_runtime.h>
#include <hip/hip_bf16.h>

// RNNColorbot round 4: sequence-length sort + early-exit.
// Rows are sorted by descending seqlen (device counting sort) and the LSTM
// runs in permuted row space; at step t only rows with len > t are live, and
// they form a prefix, so batch-tiles with b0 >= cnt[t] exit immediately.
// Expected work ~= 57% of the dense schedule; per-row math is bit-identical.
// Everything else (BK=128, gate-16 permutation, swizzled LDS +
// global_load_lds x16 staging) unchanged from round 3.

typedef __hip_bfloat16 bf16;
typedef __attribute__((ext_vector_type(8))) short bfrag8;   // 8 bf16 = 4 VGPRs
typedef __attribute__((ext_vector_type(4))) float accf4;    // MFMA accum

#define BATCH 512
#define TSTEPS 128
#define DIN 256
#define H 1024
#define NG 4096   // 4*H gate columns

__device__ __forceinline__ float sigm(float x) { return 1.0f / (1.0f + __expf(-x)); }
__device__ __forceinline__ float tanh_f(float x) {
    float a = fabsf(x);
    float e = __expf(-2.0f * a);
    float t = (1.0f - e) / (1.0f + e);
    return x < 0.0f ? -t : t;
}
__device__ __forceinline__ unsigned short bfr16(float x) {
    bf16 h = __float2bfloat16(x);
    return *(unsigned short*)&h;
}
// async global->LDS, 16B/lane. HW dest = wave-uniform LDS base + lane*16.
__device__ __forceinline__ void gll16(const void* g, void* l) {
    __builtin_amdgcn_global_load_lds(
        (const __attribute__((address_space(1))) unsigned int*)g,
        (__attribute__((address_space(3))) unsigned int*)l, 16, 0, 0);
}

// ---------------------------------------------------------------------------
// Repack [W;U] (fp32, K x 4096) -> Bp bf16 [KT][4096][128], gate-16 permuted:
//   new col n -> orig ((n>>4)&3)*1024 + (n>>7)*32 + ((n>>6)&1)*16 + (n&15)
// i.e. each 64-col wave tile = gates [i|f|g|o] x 16 h-cols. XOR-swizzled in
// 16B chunks: chunk kc of row n stored at position kc ^ (n&7) (bit3 kept),
// so global layout == LDS layout and global_load_lds copies linearly.
// ---------------------------------------------------------------------------
__global__ void k_repack(const float* __restrict__ W, const float* __restrict__ U,
                         bf16* __restrict__ Bp, int KIN)
{
    __shared__ float tile[128][65];
    int kt = blockIdx.x, nt = blockIdx.y;
    int lane = threadIdx.x;     // 64 threads
    int n = nt * 64 + lane;
    int orig = ((n >> 4) & 3) * 1024 + (n >> 7) * 32 + ((n >> 6) & 1) * 16 + (n & 15);
    for (int j = 0; j < 128; ++j) {
        int k = kt * 128 + j;
        tile[j][lane] = (k < KIN) ? W[(size_t)k * NG + orig]
                                  : U[(size_t)(k - KIN) * NG + orig];
    }
    __syncthreads();
    for (int u = 0; u < 16; ++u) {
        int cid = u * 64 + lane;           // 1024 chunks
        int nloc = cid >> 4;
        int pos = cid & 15;
        int nn = nt * 64 + nloc;
        int kc = pos ^ (nn & 7);           // logical chunk stored here
        alignas(16) unsigned short pk[8];
        #pragma unroll
        for (int jj = 0; jj < 8; ++jj) pk[jj] = bfr16(tile[kc * 8 + jj][nloc]);
        *(int4*)(Bp + ((size_t)kt * NG + nn) * 128 + pos * 8) = *(int4*)pk;
    }
}

// ---------------------------------------------------------------------------
// Counting sort of the 512 rows by descending seqlen.
//   perm[pos] = original row index (descending len, arbitrary order in ties)
//   cnt[t]    = #rows with len > t  (= #rows still live at step t)
// ---------------------------------------------------------------------------
__global__ void k_sort(const int* __restrict__ seqlen, int* __restrict__ perm,
                       int* __restrict__ cnt)
{
    __shared__ int hist[129];
    __shared__ int base[129];
    __shared__ int cur[129];
    int tid = threadIdx.x;          // 512 threads
    if (tid < 129) { hist[tid] = 0; cur[tid] = 0; }
    __syncthreads();
    int len = seqlen[tid];          // len in [1,128]
    atomicAdd(&hist[len], 1);
    __syncthreads();
    if (tid == 0) {
        int acc = 0;
        for (int l = 128; l >= 1; --l) { base[l] = acc; acc += hist[l]; }
        base[0] = acc;              // = 512
    }
    __syncthreads();
    int pos = base[len] + atomicAdd(&cur[len], 1);
    perm[pos] = tid;
    if (tid < 128) cnt[tid] = base[tid];   // #rows with len > t
}

// ---------------------------------------------------------------------------
// Fused LSTM step kernel. 256 threads: 64 batch rows x 128 gate cols, BK=128,
// 4 waves (wave tile 32x64 = all 4 gates for 16 h-cols), 16x16x32 bf16 MFMA.
// Cell update is register-resident (gates land in acc[mt][gate][reg]).
// Grid 512 = two jobs (L2 at t, L1 at t+1) -> 2 blocks/CU.
// Batch rows are in perm space; tiles with b0 >= cnt[t] exit immediately.
// ---------------------------------------------------------------------------
struct StepJob {
    const float* Xf;      // L1: fp32 x source (chars + t*DIN), else null
    const bf16* A0;       // first-K bf16 source (L2: h1[t]); swizzled
    const bf16* A1;       // recurrent h-prev source; swizzled
    const bf16* Bp;       // weights (gate-16 permuted + swizzled)
    const float* bias;    // [4096] original gate order
    float* C;             // fp32 cell state [512][1024] (perm space)
    bf16* Hout;           // h output, written SWIZZLED (perm space)
    float* hidden;        // L2: fp32 gather target (linear, ORIGINAL space)
    const int* seqlen;    // L2 (original space)
    const int* perm;      // perm[r] = original row of permuted row r
    const int* cnt;       // cnt[t] = live rows at step t
    int xstride;          // elems per row of Xf
    int ksplit;           // 256 (L1) / 1024 (L2)
    int KT;               // 10 / 16 rounds of BK=128
    int t;
};

__global__ __launch_bounds__(256, 2) void k_step(StepJob j0, StepJob j1)
{
    __shared__ __align__(16) bf16 Alds[64 * 128];    // 16 KB, swizzled
    __shared__ __align__(16) bf16 Blds[128 * 128];   // 32 KB, swizzled

    const StepJob jb = (blockIdx.x >> 8) ? j1 : j0;
    int bi = blockIdx.x & 255;
    int b0 = (bi >> 5) * 64;
    if (b0 >= jb.cnt[jb.t]) return;     // tile fully past its last live row

    int tid = threadIdx.x;
    int wv = tid >> 6, lane = tid & 63;
    int ntile = bi & 31;                // consistent ntile -> XCD mapping
    int n0 = ntile * 128;
    int mw = (wv & 1) * 32;
    int nw = (wv >> 1) * 64;
    int c = lane & 15, q = lane >> 4;

    const accf4 zero4 = {0.f, 0.f, 0.f, 0.f};
    accf4 acc[2][4];
    #pragma unroll
    for (int i = 0; i < 2; ++i)
        #pragma unroll
        for (int j = 0; j < 4; ++j) acc[i][j] = zero4;

    for (int kt = 0; kt < jb.KT; ++kt) {
        int k0 = kt << 7;
        // ---- stage A tile [64 rows][128 k] (swizzled) ----
        if (jb.Xf && k0 < jb.ksplit) {
            // fp32 -> bf16 convert path (L1 x-tiles; kt 0..1), perm-gathered
            #pragma unroll
            for (int uu = 0; uu < 4; ++uu) {
                int u = uu * 256 + tid;            // chunk id 0..1023
                int r = u >> 4;                    // row (perm space)
                int pos = u & 15;                  // swizzled position
                int kc = pos ^ (r & 7);            // logical k-chunk
                const float* src = jb.Xf + (size_t)jb.perm[b0 + r] * jb.xstride + k0 + kc * 8;
                float4 va = *(const float4*)src;
                float4 vb = *(const float4*)(src + 4);
                alignas(16) unsigned short pk[8];
                pk[0] = bfr16(va.x); pk[1] = bfr16(va.y);
                pk[2] = bfr16(va.z); pk[3] = bfr16(va.w);
                pk[4] = bfr16(vb.x); pk[5] = bfr16(vb.y);
                pk[6] = bfr16(vb.z); pk[7] = bfr16(vb.w);
                *(int4*)((char*)Alds + u * 16) = *(int4*)pk;
            }
        } else {
            const bf16* Asrc; int kk0;
            if (k0 < jb.ksplit) { Asrc = jb.A0; kk0 = k0; }
            else                { Asrc = jb.A1; kk0 = k0 - jb.ksplit; }
            // source already swizzled -> linear 256B-per-row copy
            #pragma unroll
            for (int cc = 0; cc < 4; ++cc) {
                int ob = wv * 4096 + cc * 1024;
                int o = ob + lane * 16;
                int r = o >> 8;
                const char* g = (const char*)Asrc + (size_t)(b0 + r) * (H * 2) + kk0 * 2 + (o & 255);
                gll16(g, (char*)Alds + ob);
            }
        }
        // ---- stage B tile: contiguous 32 KB (pre-swizzled in global) ----
        const char* Bg = (const char*)jb.Bp + ((size_t)kt * NG + n0) * 256;
        #pragma unroll
        for (int cc = 0; cc < 8; ++cc) {
            int ob = wv * 8192 + cc * 1024;
            gll16(Bg + ob + lane * 16, (char*)Blds + ob);
        }
        __syncthreads();
        // ---- MFMA: 4 k-steps of 32, swizzle-decoded fragment reads ----
        #pragma unroll
        for (int kk = 0; kk < 128; kk += 32) {
            int kc = (kk >> 3) + q;                  // logical chunk 0..15
            int ra = mw + c;
            int pa = (kc ^ (ra & 7)) << 3;           // (ra+16)&7 == ra&7
            bfrag8 af0 = *(const bfrag8*)(Alds + ra * 128 + pa);
            bfrag8 af1 = *(const bfrag8*)(Alds + (ra + 16) * 128 + pa);
            #pragma unroll
            for (int nt = 0; nt < 4; ++nt) {
                int nn = nw + nt * 16 + c;
                bfrag8 bfv = *(const bfrag8*)(Blds + nn * 128 + ((kc ^ (nn & 7)) << 3));
                acc[0][nt] = __builtin_amdgcn_mfma_f32_16x16x32_bf16(af0, bfv, acc[0][nt], 0, 0, 0);
                acc[1][nt] = __builtin_amdgcn_mfma_f32_16x16x32_bf16(af1, bfv, acc[1][nt], 0, 0, 0);
            }
        }
        __syncthreads();
    }

    // ---- register-resident cell update ----
    // acc[mt][gate][reg]: row = mw+mt*16+q*4+reg, hcol = ntile*32+(wv>>1)*16+c
    int hcol = ntile * 32 + (wv >> 1) * 16 + c;
    float bi_ = jb.bias[hcol],         bf_ = jb.bias[H + hcol];
    float bg_ = jb.bias[2 * H + hcol], bo_ = jb.bias[3 * H + hcol];
    int seg = hcol & ~127;
    int kc_ = (hcol & 127) >> 3;
    int jl = hcol & 7;
    #pragma unroll
    for (int mt = 0; mt < 2; ++mt) {
        #pragma unroll
        for (int reg = 0; reg < 4; ++reg) {
            int b = b0 + mw + mt * 16 + q * 4 + reg;
            float ig = sigm(acc[mt][0][reg] + bi_);
            float fg = sigm(acc[mt][1][reg] + bf_);
            float gv = tanh_f(acc[mt][2][reg] + bg_);
            float og = sigm(acc[mt][3][reg] + bo_);
            size_t ci = (size_t)b * H + hcol;
            float cv = fg * jb.C[ci] + ig * gv;
            jb.C[ci] = cv;
            float h = og * tanh_f(cv);
            // store h pre-swizzled (only ever read as an A-tile)
            jb.Hout[(size_t)b * H + seg + ((kc_ ^ (b & 7)) << 3) + jl] = __float2bfloat16(h);
            if (jb.hidden) {
                int pb = jb.perm[b];
                if (jb.seqlen[pb] - 1 == jb.t)
                    jb.hidden[(size_t)pb * H + hcol] = h;   // linear, orig space
            }
        }
    }
}

// ---------------------------------------------------------------------------
// out[b][l] = relu(hidden[b]·Wd[:,l] + bd[l]), 512 blocks x 1 wave
// ---------------------------------------------------------------------------
__global__ void k_final(const float* __restrict__ hidden, const float* __restrict__ Wd,
                        const float* __restrict__ bd, float* __restrict__ out)
{
    int b = blockIdx.x;
    int l = threadIdx.x;
    float p0 = 0.f, p1 = 0.f, p2 = 0.f;
    for (int jj = l; jj < H; jj += 64) {
        float hv = hidden[(size_t)b * H + jj];
        p0 += hv * Wd[jj * 3 + 0];
        p1 += hv * Wd[jj * 3 + 1];
        p2 += hv * Wd[jj * 3 + 2];
    }
    #pragma unroll
    for (int off = 32; off > 0; off >>= 1) {
        p0 += __shfl_down(p0, off);
        p1 += __shfl_down(p1, off);
        p2 += __shfl_down(p2, off);
    }
    if (l == 0) {
        out[b * 3 + 0] = fmaxf(p0 + bd[0], 0.f);
        out[b * 3 + 1] = fmaxf(p1 + bd[1], 0.f);
        out[b * 3 + 2] = fmaxf(p2 + bd[2], 0.f);
    }
}

extern "C" void kernel_launch(void* const* d_in, const int* in_sizes, int n_in,
                              void* d_out, int out_size, void* d_ws, size_t ws_size,
                              hipStream_t stream)
{
    const float* chars = (const float*)d_in[0];
    const int* seqlen  = (const int*)d_in[1];
    const float* W1 = (const float*)d_in[2];
    const float* U1 = (const float*)d_in[3];
    const float* b1 = (const float*)d_in[4];
    const float* W2 = (const float*)d_in[5];
    const float* U2 = (const float*)d_in[6];
    const float* b2 = (const float*)d_in[7];
    const float* Wd = (const float*)d_in[8];
    const float* bd = (const float*)d_in[9];
    float* out = (float*)d_out;

    char* ws = (char*)d_ws;
    size_t off = 0;
    bf16* Bp1 = (bf16*)(ws + off); off += (size_t)10 * NG * 128 * 2;  // 10.0 MB
    bf16* Bp2 = (bf16*)(ws + off); off += (size_t)16 * NG * 128 * 2;  // 16.0 MB
    bf16* h1  = (bf16*)(ws + off); off += (size_t)2 * BATCH * H * 2;  // 2 MB ping-pong
    bf16* h2  = (bf16*)(ws + off); off += (size_t)2 * BATCH * H * 2;  // 2 MB
    float* c1 = (float*)(ws + off); off += (size_t)BATCH * H * 4;     // 2 MB
    float* c2 = (float*)(ws + off); off += (size_t)BATCH * H * 4;     // 2 MB
    float* hidden = (float*)(ws + off); off += (size_t)BATCH * H * 4; // 2 MB
    int* perm = (int*)(ws + off); off += BATCH * 4;                   // 2 KB
    int* cntA = (int*)(ws + off); off += TSTEPS * 4;                  // 512 B
    if (ws_size < off) return;  // ~36 MB needed

    hipMemsetAsync(h1, 0, (size_t)2 * BATCH * H * 2, stream);
    hipMemsetAsync(h2, 0, (size_t)2 * BATCH * H * 2, stream);
    hipMemsetAsync(c1, 0, (size_t)BATCH * H * 4, stream);
    hipMemsetAsync(c2, 0, (size_t)BATCH * H * 4, stream);

    k_repack<<<dim3(10, 64), 64, 0, stream>>>(W1, U1, Bp1, 256);
    k_repack<<<dim3(16, 64), 64, 0, stream>>>(W2, U2, Bp2, 1024);
    k_sort<<<1, 512, 0, stream>>>(seqlen, perm, cntA);

    const size_t HS = (size_t)BATCH * H;

    auto mkL1 = [&](int s) {
        StepJob J;
        J.Xf = chars + (size_t)s * DIN;  J.xstride = TSTEPS * DIN;
        J.A0 = nullptr;
        J.A1 = h1 + (size_t)((s + 1) & 1) * HS;   // h1[s-1]
        J.Bp = Bp1; J.bias = b1; J.C = c1;
        J.Hout = h1 + (size_t)(s & 1) * HS;       // h1[s]
        J.hidden = nullptr; J.seqlen = nullptr;
        J.perm = perm; J.cnt = cntA;
        J.ksplit = 256; J.KT = 10; J.t = s;
        return J;
    };
    auto mkL2 = [&](int s) {
        StepJob J;
        J.Xf = nullptr; J.xstride = 0;
        J.A0 = h1 + (size_t)(s & 1) * HS;         // h1[s]
        J.A1 = h2 + (size_t)((s + 1) & 1) * HS;   // h2[s-1]
        J.Bp = Bp2; J.bias = b2; J.C = c2;
        J.Hout = h2 + (size_t)(s & 1) * HS;       // h2[s]
        J.hidden = hidden; J.seqlen = seqlen;
        J.perm = perm; J.cnt = cntA;
        J.ksplit = 1024; J.KT = 16; J.t = s;
        return J;
    };

    StepJob first = mkL1(0);
    k_step<<<256, 256, 0, stream>>>(first, first);
    for (int t = 0; t < TSTEPS - 1; ++t) {
        k_step<<<512, 256, 0, stream>>>(mkL2(t), mkL1(t + 1));
    }
    StepJob last = mkL2(TSTEPS - 1);
    k_step<<<256, 256, 0, stream>>>(last, last);
    k_final<<<512, 64, 0, stream>>>(hidden, Wd, bd, out);
}

// Round 2
// 3755.556 us; speedup vs baseline: 1.0146x; 1.0146x over previous
//
#include <hip/hip_runtime.h>
#include <hip/hip_bf16.h>

// RNNColorbot round 5: early-exit LOAD BALANCE fix.
// Round 4's sort+early-exit was neutral: live blocks (a prefix in bi space)
// clustered 2-deep on the low CUs while the rest idled, so the per-launch
// critical path stayed at 2 blocks/CU. New bi -> (btile,ntile) mapping puts
// btile in the high CU-slot bits (spreads live tiles 1-per-CU as cnt shrinks),
// keeps ntile's low 3 bits in bi&7 (same-ntile -> same-XCD weight reuse), and
// reverses job1's btile so a CU's two blocks are live-complementary.
// Everything else (BK=128, gate-16 permutation, swizzled LDS +
// global_load_lds x16 staging, register-resident cell update) unchanged.

typedef __hip_bfloat16 bf16;
typedef __attribute__((ext_vector_type(8))) short bfrag8;   // 8 bf16 = 4 VGPRs
typedef __attribute__((ext_vector_type(4))) float accf4;    // MFMA accum

#define BATCH 512
#define TSTEPS 128
#define DIN 256
#define H 1024
#define NG 4096   // 4*H gate columns

__device__ __forceinline__ float sigm(float x) { return 1.0f / (1.0f + __expf(-x)); }
__device__ __forceinline__ float tanh_f(float x) {
    float a = fabsf(x);
    float e = __expf(-2.0f * a);
    float t = (1.0f - e) / (1.0f + e);
    return x < 0.0f ? -t : t;
}
__device__ __forceinline__ unsigned short bfr16(float x) {
    bf16 h = __float2bfloat16(x);
    return *(unsigned short*)&h;
}
// async global->LDS, 16B/lane. HW dest = wave-uniform LDS base + lane*16.
__device__ __forceinline__ void gll16(const void* g, void* l) {
    __builtin_amdgcn_global_load_lds(
        (const __attribute__((address_space(1))) unsigned int*)g,
        (__attribute__((address_space(3))) unsigned int*)l, 16, 0, 0);
}

// ---------------------------------------------------------------------------
// Repack [W;U] (fp32, K x 4096) -> Bp bf16 [KT][4096][128], gate-16 permuted:
//   new col n -> orig ((n>>4)&3)*1024 + (n>>7)*32 + ((n>>6)&1)*16 + (n&15)
// i.e. each 64-col wave tile = gates [i|f|g|o] x 16 h-cols. XOR-swizzled in
// 16B chunks: chunk kc of row n stored at position kc ^ (n&7) (bit3 kept),
// so global layout == LDS layout and global_load_lds copies linearly.
// ---------------------------------------------------------------------------
__global__ void k_repack(const float* __restrict__ W, const float* __restrict__ U,
                         bf16* __restrict__ Bp, int KIN)
{
    __shared__ float tile[128][65];
    int kt = blockIdx.x, nt = blockIdx.y;
    int lane = threadIdx.x;     // 64 threads
    int n = nt * 64 + lane;
    int orig = ((n >> 4) & 3) * 1024 + (n >> 7) * 32 + ((n >> 6) & 1) * 16 + (n & 15);
    for (int j = 0; j < 128; ++j) {
        int k = kt * 128 + j;
        tile[j][lane] = (k < KIN) ? W[(size_t)k * NG + orig]
                                  : U[(size_t)(k - KIN) * NG + orig];
    }
    __syncthreads();
    for (int u = 0; u < 16; ++u) {
        int cid = u * 64 + lane;           // 1024 chunks
        int nloc = cid >> 4;
        int pos = cid & 15;
        int nn = nt * 64 + nloc;
        int kc = pos ^ (nn & 7);           // logical chunk stored here
        alignas(16) unsigned short pk[8];
        #pragma unroll
        for (int jj = 0; jj < 8; ++jj) pk[jj] = bfr16(tile[kc * 8 + jj][nloc]);
        *(int4*)(Bp + ((size_t)kt * NG + nn) * 128 + pos * 8) = *(int4*)pk;
    }
}

// ---------------------------------------------------------------------------
// Counting sort of the 512 rows by descending seqlen.
//   perm[pos] = original row index (descending len, arbitrary order in ties)
//   cnt[t]    = #rows with len > t  (= #rows still live at step t)
// ---------------------------------------------------------------------------
__global__ void k_sort(const int* __restrict__ seqlen, int* __restrict__ perm,
                       int* __restrict__ cnt)
{
    __shared__ int hist[129];
    __shared__ int base[129];
    __shared__ int cur[129];
    int tid = threadIdx.x;          // 512 threads
    if (tid < 129) { hist[tid] = 0; cur[tid] = 0; }
    __syncthreads();
    int len = seqlen[tid];          // len in [1,128]
    atomicAdd(&hist[len], 1);
    __syncthreads();
    if (tid == 0) {
        int acc = 0;
        for (int l = 128; l >= 1; --l) { base[l] = acc; acc += hist[l]; }
        base[0] = acc;              // = 512
    }
    __syncthreads();
    int pos = base[len] + atomicAdd(&cur[len], 1);
    perm[pos] = tid;
    if (tid < 128) cnt[tid] = base[tid];   // #rows with len > t
}

// ---------------------------------------------------------------------------
// Fused LSTM step kernel. 256 threads: 64 batch rows x 128 gate cols, BK=128,
// 4 waves (wave tile 32x64 = all 4 gates for 16 h-cols), 16x16x32 bf16 MFMA.
// Cell update is register-resident (gates land in acc[mt][gate][reg]).
// Grid 512 = two jobs (L2 at t, L1 at t+1) -> 2 blocks/CU.
// Batch rows are in perm space; tiles with b0 >= cnt[t] exit immediately.
// bi -> (btile,ntile) mapping (per job, bi in [0,256)):
//   xcd = bi&7, s = bi>>3, btr = s>>2, btile = job ? 7-btr : btr,
//   ntile = ((s&3)<<3) | xcd
// - same ntile => same bi%8 => same XCD (weight L2 reuse, ~3.3 MB/XCD)
// - live btiles occupy distinct CU slots => 1 live block/CU when
//   ceil(cnt0/64)+ceil(cnt1/64) <= 8 (job1 btile reversed for complement)
// ---------------------------------------------------------------------------
struct StepJob {
    const float* Xf;      // L1: fp32 x source (chars + t*DIN), else null
    const bf16* A0;       // first-K bf16 source (L2: h1[t]); swizzled
    const bf16* A1;       // recurrent h-prev source; swizzled
    const bf16* Bp;       // weights (gate-16 permuted + swizzled)
    const float* bias;    // [4096] original gate order
    float* C;             // fp32 cell state [512][1024] (perm space)
    bf16* Hout;           // h output, written SWIZZLED (perm space)
    float* hidden;        // L2: fp32 gather target (linear, ORIGINAL space)
    const int* seqlen;    // L2 (original space)
    const int* perm;      // perm[r] = original row of permuted row r
    const int* cnt;       // cnt[t] = live rows at step t
    int xstride;          // elems per row of Xf
    int ksplit;           // 256 (L1) / 1024 (L2)
    int KT;               // 10 / 16 rounds of BK=128
    int t;
};

__global__ __launch_bounds__(256, 2) void k_step(StepJob j0, StepJob j1)
{
    __shared__ __align__(16) bf16 Alds[64 * 128];    // 16 KB, swizzled
    __shared__ __align__(16) bf16 Blds[128 * 128];   // 32 KB, swizzled

    int jidx = blockIdx.x >> 8;
    const StepJob jb = jidx ? j1 : j0;
    int bi = blockIdx.x & 255;
    int xcd = bi & 7;
    int s = bi >> 3;
    int btr = s >> 2;
    int btile = jidx ? (7 - btr) : btr;
    int ntile = ((s & 3) << 3) | xcd;
    int b0 = btile * 64;
    if (b0 >= jb.cnt[jb.t]) return;     // tile fully past its last live row

    int tid = threadIdx.x;
    int wv = tid >> 6, lane = tid & 63;
    int n0 = ntile * 128;
    int mw = (wv & 1) * 32;
    int nw = (wv >> 1) * 64;
    int c = lane & 15, q = lane >> 4;

    const accf4 zero4 = {0.f, 0.f, 0.f, 0.f};
    accf4 acc[2][4];
    #pragma unroll
    for (int i = 0; i < 2; ++i)
        #pragma unroll
        for (int j = 0; j < 4; ++j) acc[i][j] = zero4;

    for (int kt = 0; kt < jb.KT; ++kt) {
        int k0 = kt << 7;
        // ---- stage A tile [64 rows][128 k] (swizzled) ----
        if (jb.Xf && k0 < jb.ksplit) {
            // fp32 -> bf16 convert path (L1 x-tiles; kt 0..1), perm-gathered
            #pragma unroll
            for (int uu = 0; uu < 4; ++uu) {
                int u = uu * 256 + tid;            // chunk id 0..1023
                int r = u >> 4;                    // row (perm space)
                int pos = u & 15;                  // swizzled position
                int kc = pos ^ (r & 7);            // logical k-chunk
                const float* src = jb.Xf + (size_t)jb.perm[b0 + r] * jb.xstride + k0 + kc * 8;
                float4 va = *(const float4*)src;
                float4 vb = *(const float4*)(src + 4);
                alignas(16) unsigned short pk[8];
                pk[0] = bfr16(va.x); pk[1] = bfr16(va.y);
                pk[2] = bfr16(va.z); pk[3] = bfr16(va.w);
                pk[4] = bfr16(vb.x); pk[5] = bfr16(vb.y);
                pk[6] = bfr16(vb.z); pk[7] = bfr16(vb.w);
                *(int4*)((char*)Alds + u * 16) = *(int4*)pk;
            }
        } else {
            const bf16* Asrc; int kk0;
            if (k0 < jb.ksplit) { Asrc = jb.A0; kk0 = k0; }
            else                { Asrc = jb.A1; kk0 = k0 - jb.ksplit; }
            // source already swizzled -> linear 256B-per-row copy
            #pragma unroll
            for (int cc = 0; cc < 4; ++cc) {
                int ob = wv * 4096 + cc * 1024;
                int o = ob + lane * 16;
                int r = o >> 8;
                const char* g = (const char*)Asrc + (size_t)(b0 + r) * (H * 2) + kk0 * 2 + (o & 255);
                gll16(g, (char*)Alds + ob);
            }
        }
        // ---- stage B tile: contiguous 32 KB (pre-swizzled in global) ----
        const char* Bg = (const char*)jb.Bp + ((size_t)kt * NG + n0) * 256;
        #pragma unroll
        for (int cc = 0; cc < 8; ++cc) {
            int ob = wv * 8192 + cc * 1024;
            gll16(Bg + ob + lane * 16, (char*)Blds + ob);
        }
        __syncthreads();
        // ---- MFMA: 4 k-steps of 32, swizzle-decoded fragment reads ----
        #pragma unroll
        for (int kk = 0; kk < 128; kk += 32) {
            int kc = (kk >> 3) + q;                  // logical chunk 0..15
            int ra = mw + c;
            int pa = (kc ^ (ra & 7)) << 3;           // (ra+16)&7 == ra&7
            bfrag8 af0 = *(const bfrag8*)(Alds + ra * 128 + pa);
            bfrag8 af1 = *(const bfrag8*)(Alds + (ra + 16) * 128 + pa);
            #pragma unroll
            for (int nt = 0; nt < 4; ++nt) {
                int nn = nw + nt * 16 + c;
                bfrag8 bfv = *(const bfrag8*)(Blds + nn * 128 + ((kc ^ (nn & 7)) << 3));
                acc[0][nt] = __builtin_amdgcn_mfma_f32_16x16x32_bf16(af0, bfv, acc[0][nt], 0, 0, 0);
                acc[1][nt] = __builtin_amdgcn_mfma_f32_16x16x32_bf16(af1, bfv, acc[1][nt], 0, 0, 0);
            }
        }
        __syncthreads();
    }

    // ---- register-resident cell update ----
    // acc[mt][gate][reg]: row = mw+mt*16+q*4+reg, hcol = ntile*32+(wv>>1)*16+c
    int hcol = ntile * 32 + (wv >> 1) * 16 + c;
    float bi_ = jb.bias[hcol],         bf_ = jb.bias[H + hcol];
    float bg_ = jb.bias[2 * H + hcol], bo_ = jb.bias[3 * H + hcol];
    int seg = hcol & ~127;
    int kc_ = (hcol & 127) >> 3;
    int jl = hcol & 7;
    #pragma unroll
    for (int mt = 0; mt < 2; ++mt) {
        #pragma unroll
        for (int reg = 0; reg < 4; ++reg) {
            int b = b0 + mw + mt * 16 + q * 4 + reg;
            float ig = sigm(acc[mt][0][reg] + bi_);
            float fg = sigm(acc[mt][1][reg] + bf_);
            float gv = tanh_f(acc[mt][2][reg] + bg_);
            float og = sigm(acc[mt][3][reg] + bo_);
            size_t ci = (size_t)b * H + hcol;
            float cv = fg * jb.C[ci] + ig * gv;
            jb.C[ci] = cv;
            float h = og * tanh_f(cv);
            // store h pre-swizzled (only ever read as an A-tile)
            jb.Hout[(size_t)b * H + seg + ((kc_ ^ (b & 7)) << 3) + jl] = __float2bfloat16(h);
            if (jb.hidden) {
                int pb = jb.perm[b];
                if (jb.seqlen[pb] - 1 == jb.t)
                    jb.hidden[(size_t)pb * H + hcol] = h;   // linear, orig space
            }
        }
    }
}

// ---------------------------------------------------------------------------
// out[b][l] = relu(hidden[b]·Wd[:,l] + bd[l]), 512 blocks x 1 wave
// ---------------------------------------------------------------------------
__global__ void k_final(const float* __restrict__ hidden, const float* __restrict__ Wd,
                        const float* __restrict__ bd, float* __restrict__ out)
{
    int b = blockIdx.x;
    int l = threadIdx.x;
    float p0 = 0.f, p1 = 0.f, p2 = 0.f;
    for (int jj = l; jj < H; jj += 64) {
        float hv = hidden[(size_t)b * H + jj];
        p0 += hv * Wd[jj * 3 + 0];
        p1 += hv * Wd[jj * 3 + 1];
        p2 += hv * Wd[jj * 3 + 2];
    }
    #pragma unroll
    for (int off = 32; off > 0; off >>= 1) {
        p0 += __shfl_down(p0, off);
        p1 += __shfl_down(p1, off);
        p2 += __shfl_down(p2, off);
    }
    if (l == 0) {
        out[b * 3 + 0] = fmaxf(p0 + bd[0], 0.f);
        out[b * 3 + 1] = fmaxf(p1 + bd[1], 0.f);
        out[b * 3 + 2] = fmaxf(p2 + bd[2], 0.f);
    }
}

extern "C" void kernel_launch(void* const* d_in, const int* in_sizes, int n_in,
                              void* d_out, int out_size, void* d_ws, size_t ws_size,
                              hipStream_t stream)
{
    const float* chars = (const float*)d_in[0];
    const int* seqlen  = (const int*)d_in[1];
    const float* W1 = (const float*)d_in[2];
    const float* U1 = (const float*)d_in[3];
    const float* b1 = (const float*)d_in[4];
    const float* W2 = (const float*)d_in[5];
    const float* U2 = (const float*)d_in[6];
    const float* b2 = (const float*)d_in[7];
    const float* Wd = (const float*)d_in[8];
    const float* bd = (const float*)d_in[9];
    float* out = (float*)d_out;

    char* ws = (char*)d_ws;
    size_t off = 0;
    bf16* Bp1 = (bf16*)(ws + off); off += (size_t)10 * NG * 128 * 2;  // 10.0 MB
    bf16* Bp2 = (bf16*)(ws + off); off += (size_t)16 * NG * 128 * 2;  // 16.0 MB
    bf16* h1  = (bf16*)(ws + off); off += (size_t)2 * BATCH * H * 2;  // 2 MB ping-pong
    bf16* h2  = (bf16*)(ws + off); off += (size_t)2 * BATCH * H * 2;  // 2 MB
    float* c1 = (float*)(ws + off); off += (size_t)BATCH * H * 4;     // 2 MB
    float* c2 = (float*)(ws + off); off += (size_t)BATCH * H * 4;     // 2 MB
    float* hidden = (float*)(ws + off); off += (size_t)BATCH * H * 4; // 2 MB
    int* perm = (int*)(ws + off); off += BATCH * 4;                   // 2 KB
    int* cntA = (int*)(ws + off); off += TSTEPS * 4;                  // 512 B
    if (ws_size < off) return;  // ~36 MB needed

    hipMemsetAsync(h1, 0, (size_t)2 * BATCH * H * 2, stream);
    hipMemsetAsync(h2, 0, (size_t)2 * BATCH * H * 2, stream);
    hipMemsetAsync(c1, 0, (size_t)BATCH * H * 4, stream);
    hipMemsetAsync(c2, 0, (size_t)BATCH * H * 4, stream);

    k_repack<<<dim3(10, 64), 64, 0, stream>>>(W1, U1, Bp1, 256);
    k_repack<<<dim3(16, 64), 64, 0, stream>>>(W2, U2, Bp2, 1024);
    k_sort<<<1, 512, 0, stream>>>(seqlen, perm, cntA);

    const size_t HS = (size_t)BATCH * H;

    auto mkL1 = [&](int s) {
        StepJob J;
        J.Xf = chars + (size_t)s * DIN;  J.xstride = TSTEPS * DIN;
        J.A0 = nullptr;
        J.A1 = h1 + (size_t)((s + 1) & 1) * HS;   // h1[s-1]
        J.Bp = Bp1; J.bias = b1; J.C = c1;
        J.Hout = h1 + (size_t)(s & 1) * HS;       // h1[s]
        J.hidden = nullptr; J.seqlen = nullptr;
        J.perm = perm; J.cnt = cntA;
        J.ksplit = 256; J.KT = 10; J.t = s;
        return J;
    };
    auto mkL2 = [&](int s) {
        StepJob J;
        J.Xf = nullptr; J.xstride = 0;
        J.A0 = h1 + (size_t)(s & 1) * HS;         // h1[s]
        J.A1 = h2 + (size_t)((s + 1) & 1) * HS;   // h2[s-1]
        J.Bp = Bp2; J.bias = b2; J.C = c2;
        J.Hout = h2 + (size_t)(s & 1) * HS;       // h2[s]
        J.hidden = hidden; J.seqlen = seqlen;
        J.perm = perm; J.cnt = cntA;
        J.ksplit = 1024; J.KT = 16; J.t = s;
        return J;
    };

    StepJob first = mkL1(0);
    k_step<<<256, 256, 0, stream>>>(first, first);
    for (int t = 0; t < TSTEPS - 1; ++t) {
        k_step<<<512, 256, 0, stream>>>(mkL2(t), mkL1(t + 1));
    }
    StepJob last = mkL2(TSTEPS - 1);
    k_step<<<256, 256, 0, stream>>>(last, last);
    k_final<<<512, 64, 0, stream>>>(hidden, Wd, bd, out);
}